// Round 9
// baseline (678.441 us; speedup 1.0000x reference)
//
#include <hip/hip_runtime.h>
#include <stddef.h>

// Sizes (fixed by the problem)
#define BB   128      // batch
#define TT   512      // time
#define VV   32000    // vocab
#define DD   300      // emb dim
#define HH   128      // hidden
#define G3   384      // 3*H
#define NC   768      // 2*3*H (fwd+bwd projected gates)
#define MB   16       // batches per scan block (MFMA M-tile)

typedef __fp16 half_t;
typedef __fp16 half2_t __attribute__((ext_vector_type(2)));

typedef _Float16 f16x8 __attribute__((ext_vector_type(8)));   // MFMA A/B frag
typedef float    f32x4 __attribute__((ext_vector_type(4)));   // MFMA C/D frag

// ---------------------------------------------------------------------------
// Kernel 1: P[v][g] = emb[v][:] @ Wcat[:, g] + b_i[g]   (unchanged from R8)
// ---------------------------------------------------------------------------
#define PSTR 140
__global__ __launch_bounds__(256) void proj_kernel(
    const float* __restrict__ emb,
    const float* __restrict__ Wf, const float* __restrict__ Wb,
    const float* __restrict__ bf, const float* __restrict__ bb,
    float* __restrict__ P)
{
    __shared__ __align__(16) half2_t As2[6][PSTR];   // [k2][skewed row]
    __shared__ __align__(16) half2_t Bs2[6][PSTR];   // [k2][skewed col]

    const int m0 = blockIdx.x * 128;     // vocab-row tile
    const int n0 = blockIdx.y * 128;     // output-col tile

    const float* Wsrc;
    const float* bsrc;
    int cb;
    if (n0 < G3) { Wsrc = Wf; bsrc = bf; cb = n0; }
    else         { Wsrc = Wb; bsrc = bb; cb = n0 - G3; }

    const int t  = threadIdx.x;
    const int tx = t & 15;               // col group (8 cols each)
    const int ty = t >> 4;               // row group (8 rows each)

    float acc[8][8];
    #pragma unroll
    for (int i = 0; i < 8; ++i)
        #pragma unroll
        for (int j = 0; j < 8; ++j) acc[i][j] = 0.f;

    const int aread = ty * 8 + ((ty >> 2) << 2);
    const int bread = tx * 8 + ((tx >> 2) << 2);

    for (int kt = 0; kt < 25; ++kt) {
        const int kbase = kt * 12;

        {
            int row = t & 127, ch = t >> 7;           // ch 0..1 -> k 0..7
            int srow = row + ((row >> 5) << 2);
            float4 v = *(const float4*)(emb + (size_t)(m0 + row) * DD + kbase + ch * 4);
            As2[ch * 2 + 0][srow] = __builtin_amdgcn_cvt_pkrtz(v.x, v.y);
            As2[ch * 2 + 1][srow] = __builtin_amdgcn_cvt_pkrtz(v.z, v.w);
            if (t < 128) {                            // k 8..11
                int row2 = t, srow2 = row2 + ((row2 >> 5) << 2);
                float4 v2 = *(const float4*)(emb + (size_t)(m0 + row2) * DD + kbase + 8);
                As2[4][srow2] = __builtin_amdgcn_cvt_pkrtz(v2.x, v2.y);
                As2[5][srow2] = __builtin_amdgcn_cvt_pkrtz(v2.z, v2.w);
            }
        }
        if (t < 192) {
            int k2 = t >> 5, col = (t & 31) * 4;
            int r0 = kbase + 2 * k2;
            float4 w0 = *(const float4*)(Wsrc + (size_t)r0 * G3 + cb + col);
            float4 w1 = *(const float4*)(Wsrc + (size_t)(r0 + 1) * G3 + cb + col);
            int sc = col + ((col >> 5) << 2);
            half2_t pk[4];
            pk[0] = __builtin_amdgcn_cvt_pkrtz(w0.x, w1.x);
            pk[1] = __builtin_amdgcn_cvt_pkrtz(w0.y, w1.y);
            pk[2] = __builtin_amdgcn_cvt_pkrtz(w0.z, w1.z);
            pk[3] = __builtin_amdgcn_cvt_pkrtz(w0.w, w1.w);
            *(float4*)&Bs2[k2][sc] = *(float4*)&pk[0];
        }
        __syncthreads();

        #pragma unroll
        for (int kk = 0; kk < 6; ++kk) {
            const half2_t* ap = &As2[kk][aread];
            const half2_t* bp = &Bs2[kk][bread];
            half2_t a2[8], b2[8];
            *(float4*)&a2[0] = *(const float4*)&ap[0];
            *(float4*)&a2[4] = *(const float4*)&ap[4];
            *(float4*)&b2[0] = *(const float4*)&bp[0];
            *(float4*)&b2[4] = *(const float4*)&bp[4];
            #pragma unroll
            for (int i = 0; i < 8; ++i)
                #pragma unroll
                for (int j = 0; j < 8; ++j)
                    acc[i][j] = __builtin_amdgcn_fdot2(a2[i], b2[j], acc[i][j], false);
        }
        __syncthreads();
    }

    float bias[8];
    #pragma unroll
    for (int j = 0; j < 8; ++j) bias[j] = bsrc[cb + tx * 8 + j];

    #pragma unroll
    for (int i = 0; i < 8; ++i) {
        int row = m0 + ty * 8 + i;
        float4 o0 = { acc[i][0] + bias[0], acc[i][1] + bias[1],
                      acc[i][2] + bias[2], acc[i][3] + bias[3] };
        float4 o1 = { acc[i][4] + bias[4], acc[i][5] + bias[5],
                      acc[i][6] + bias[6], acc[i][7] + bias[7] };
        float* dst = P + (size_t)row * NC + n0 + tx * 8;
        *(float4*)dst       = o0;
        *(float4*)(dst + 4) = o1;
    }
}

// ---------------------------------------------------------------------------
// Kernel 2: MFMA-batched GRU scan.
// grid (8 batch-groups, 2 dirs) = 16 blocks x 512 threads (8 waves).
// Per step per block: rec[16x384] = H[16x128] @ U[128x384] via 12
// mfma_f32_16x16x32_f16 per wave (3 gates x 4 K-tiles).
// Wave w owns N-tiles {w, 8+w, 16+w} (z, r, hh at the SAME 16-col slice)
// -> D layout (col=lane&15, row=(lane>>4)*4+reg; m89-verified) puts
// z/r/hh for (m, c) in the SAME lane -> gate math fully in-register.
// Lane (w,lg,lr): c = 16w+lr, rows m = 4*lg+i (i=0..3).
// H lives in LDS as f16 [16][136] (pad 8 -> 2-way-max bank spread),
// double-buffered; A-frag = ds_read_b128 of 8 contiguous k.
// U preloaded once as 48 VGPRs of f16 B-frags (B: k=8*(l>>4)+j, col=l&15).
// One lgkm-only barrier per step.
// ---------------------------------------------------------------------------
#define BAR() asm volatile("s_waitcnt lgkmcnt(0)\n\ts_barrier" ::: "memory")

union FragF {
    f16x8    v;      // MFMA operand
    _Float16 h[8];   // element fill
    f32x4    f4;     // 16B LDS read
};

__global__ __launch_bounds__(512) void scan_kernel(
    const int*   __restrict__ tokens,
    const float* __restrict__ state_f, const float* __restrict__ state_b,
    const float* __restrict__ Uf, const float* __restrict__ Ub,
    const float* __restrict__ bf, const float* __restrict__ bb,
    const float* __restrict__ P,
    float* __restrict__ out)
{
    const int b0 = blockIdx.x * MB;      // batch-group base
    const int d  = blockIdx.y;           // 0 = fwd, 1 = bwd
    const int t  = threadIdx.x;          // 0..511
    const int w  = t >> 6;               // wave 0..7
    const int l  = t & 63;
    const int lr = l & 15;
    const int lg = l >> 4;               // 0..3
    const int c  = w * 16 + lr;          // gate column 0..127

    const float* U  = d ? Ub : Uf;
    const float* bv = d ? bb : bf;
    const float* st = d ? state_b : state_f;
    const int    cb = d ? G3 : 0;

    __shared__ __align__(16) _Float16 Hs[2][MB][136];
    __shared__ int tok_s[MB][TT];

    // stage tokens (coalesced along t)
    for (int idx = t; idx < MB * TT; idx += 512) {
        int m = idx >> 9, ts = idx & 511;
        tok_s[m][ts] = tokens[(b0 + m) * TT + ts];
    }
    // stage initial H (f16)
    for (int idx = t; idx < MB * HH; idx += 512) {
        int m = idx >> 7, k = idx & 127;
        Hs[0][m][k] = (_Float16)st[(b0 + m) * HH + k];
    }

    // preload U fragments (B operand): B[k=8*lg+j + 32*kt][col=c(+gate*128)]
    FragF Uz[4], Ur[4], Uh[4];
    #pragma unroll
    for (int kt = 0; kt < 4; ++kt)
        #pragma unroll
        for (int j = 0; j < 8; ++j) {
            const float* Urow = U + (size_t)(kt * 32 + lg * 8 + j) * G3;
            Uz[kt].h[j] = (_Float16)Urow[c];
            Ur[kt].h[j] = (_Float16)Urow[HH + c];
            Uh[kt].h[j] = (_Float16)Urow[2 * HH + c];
        }

    const float bz = bv[G3 + c];
    const float br = bv[G3 + HH + c];
    const float bh = bv[G3 + 2 * HH + c];

    float  hprev[4];
    size_t outb[4];
    #pragma unroll
    for (int i = 0; i < 4; ++i) {
        int m = lg * 4 + i;
        hprev[i] = st[(b0 + m) * HH + c];
        outb[i]  = ((size_t)(b0 + m) * TT) * 256 + (size_t)(d * HH + c);
    }

    __syncthreads();

    // prefetch xp triples (z,r,hh) for step 0, rows m = 4*lg+i
    float xz[4], xr[4], xh[4], xz_n[4], xr_n[4], xh_n[4];
    {
        int t0 = d ? (TT - 1) : 0;
        #pragma unroll
        for (int i = 0; i < 4; ++i) {
            int tok = tok_s[lg * 4 + i][t0];
            const float* pr = P + (size_t)tok * NC + cb + c;
            xz_n[i] = pr[0]; xr_n[i] = pr[HH]; xh_n[i] = pr[2 * HH];
        }
    }

    int cur = 0;
    for (int it = 0; it < TT; ++it) {
        const int tcur = d ? (TT - 1 - it) : it;
        #pragma unroll
        for (int i = 0; i < 4; ++i) { xz[i] = xz_n[i]; xr[i] = xr_n[i]; xh[i] = xh_n[i]; }
        {   // prefetch next step's xp (last iter re-reads same row; harmless)
            int in1 = (it + 1 < TT) ? (it + 1) : it;
            int tn  = d ? (TT - 1 - in1) : in1;
            #pragma unroll
            for (int i = 0; i < 4; ++i) {
                int tok = tok_s[lg * 4 + i][tn];
                const float* pr = P + (size_t)tok * NC + cb + c;
                xz_n[i] = pr[0]; xr_n[i] = pr[HH]; xh_n[i] = pr[2 * HH];
            }
        }

        // A fragments: A[m=lr][k = 8*lg + j + 32*kt] from Hs[cur]
        FragF a[4];
        #pragma unroll
        for (int kt = 0; kt < 4; ++kt)
            a[kt].f4 = *(const f32x4*)&Hs[cur][lr][kt * 32 + lg * 8];

        f32x4 az = {0.f, 0.f, 0.f, 0.f};
        f32x4 ag = {0.f, 0.f, 0.f, 0.f};
        f32x4 ah = {0.f, 0.f, 0.f, 0.f};
        #pragma unroll
        for (int kt = 0; kt < 4; ++kt) {
            az = __builtin_amdgcn_mfma_f32_16x16x32_f16(a[kt].v, Uz[kt].v, az, 0, 0, 0);
            ag = __builtin_amdgcn_mfma_f32_16x16x32_f16(a[kt].v, Ur[kt].v, ag, 0, 0, 0);
            ah = __builtin_amdgcn_mfma_f32_16x16x32_f16(a[kt].v, Uh[kt].v, ah, 0, 0, 0);
        }

        const int nxt = cur ^ 1;
        #pragma unroll
        for (int i = 0; i < 4; ++i) {
            float z  = __builtin_amdgcn_rcpf(1.f + __expf(-(az[i] + bz + xz[i])));
            float r  = __builtin_amdgcn_rcpf(1.f + __expf(-(ag[i] + br + xr[i])));
            float ph = xh[i] + r * (ah[i] + bh);
            ph = fminf(fmaxf(ph, -15.f), 15.f);
            float e   = __expf(-2.f * ph);
            float hhv = (1.f - e) * __builtin_amdgcn_rcpf(1.f + e);   // tanh
            float hn  = z * hprev[i] + (1.f - z) * hhv;
            hprev[i] = hn;
            Hs[nxt][lg * 4 + i][c] = (_Float16)hn;
            out[outb[i] + (size_t)tcur * 256] = hn;
        }
        BAR();       // Hs[nxt] visible to all waves; Hs[cur] reads drained
        cur = nxt;
    }

    #pragma unroll
    for (int i = 0; i < 4; ++i) {
        int m = lg * 4 + i;
        // final states: [B*T*256 | h_f (B*H) | h_b (B*H)]
        out[(size_t)BB * TT * 256 + (size_t)d * BB * HH + (b0 + m) * HH + c] = hprev[i];
    }
}

// ---------------------------------------------------------------------------
extern "C" void kernel_launch(void* const* d_in, const int* in_sizes, int n_in,
                              void* d_out, int out_size, void* d_ws, size_t ws_size,
                              hipStream_t stream)
{
    const int*   tokens  = (const int*)  d_in[0];
    const float* state_f = (const float*)d_in[1];
    const float* state_b = (const float*)d_in[2];
    const float* emb     = (const float*)d_in[3];
    const float* W_f     = (const float*)d_in[4];
    const float* U_f     = (const float*)d_in[5];
    const float* b_f     = (const float*)d_in[6];
    const float* W_b     = (const float*)d_in[7];
    const float* U_b     = (const float*)d_in[8];
    const float* b_b     = (const float*)d_in[9];
    float*       out     = (float*)d_out;

    float* P = (float*)d_ws;   // needs 32000*768*4 = 98.3 MB of workspace

    dim3 gp(VV / 128, NC / 128);           // 250 x 6
    proj_kernel<<<gp, 256, 0, stream>>>(emb, W_f, W_b, b_f, b_b, P);

    dim3 gs(BB / MB, 2);                    // 8 batch-groups x 2 directions
    scan_kernel<<<gs, 512, 0, stream>>>(tokens, state_f, state_b,
                                        U_f, U_b, b_f, b_b, P, out);
}

// Round 10
// 427.587 us; speedup vs baseline: 1.5867x; 1.5867x over previous
//
#include <hip/hip_runtime.h>
#include <stddef.h>

// Sizes (fixed by the problem)
#define BB   128      // batch
#define TT   512      // time
#define VV   32000    // vocab
#define DD   300      // emb dim
#define HH   128      // hidden
#define G3   384      // 3*H
#define NC   768      // 2*3*H (fwd+bwd projected gates)

typedef __fp16 half_t;
typedef __fp16 half2_t __attribute__((ext_vector_type(2)));
typedef _Float16 f16x8 __attribute__((ext_vector_type(8)));   // MFMA A/B frag
typedef float    f32x4 __attribute__((ext_vector_type(4)));   // MFMA C/D frag

union FragF {
    f16x8    v;      // MFMA operand
    _Float16 h[8];   // element fill
    f32x4    f4;     // 16B LDS read
};

// ---------------------------------------------------------------------------
// Kernel 1: P[v][g] = emb[v][:] @ Wcat[:, g] + b_i[g] -- MFMA GEMM.
// BM=128 x BN=128 x BK=32, 256 threads (4 waves), grid 250 x 6.
// Fragment conventions (hardware-verified by R9's passing scan):
//   A: lane l holds A[row=l&15][k=8*(l>>4)+j], j=0..7 contiguous
//   B: lane l holds B[k=8*(l>>4)+j][col=l&15]
//   D: col=l&15, row=(l>>4)*4+reg
// As/Bs stored [row|col][k] so frags are single ds_read_b128; stride 40
// halves = 80B (16B-aligned, 2-way max bank alias). K=300: 10 K-tiles,
// tail (k>=300) zero-filled. Bias added in epilogue.
// ---------------------------------------------------------------------------
#define ASTR 40
__global__ __launch_bounds__(256) void proj_kernel(
    const float* __restrict__ emb,
    const float* __restrict__ Wf, const float* __restrict__ Wb,
    const float* __restrict__ bf, const float* __restrict__ bb,
    float* __restrict__ P)
{
    __shared__ __align__(16) _Float16 As[128][ASTR];
    __shared__ __align__(16) _Float16 Bs[128][ASTR];

    const int m0 = blockIdx.x * 128;     // vocab-row tile
    const int n0 = blockIdx.y * 128;     // output-col tile

    const float* Wsrc;
    const float* bsrc;
    int cb;
    if (n0 < G3) { Wsrc = Wf; bsrc = bf; cb = n0; }
    else         { Wsrc = Wb; bsrc = bb; cb = n0 - G3; }

    const int t  = threadIdx.x;
    const int w  = t >> 6;               // wave 0..3
    const int l  = t & 63;
    const int lr = l & 15;
    const int lg = l >> 4;               // 0..3

    f32x4 acc[2][8];
    #pragma unroll
    for (int i = 0; i < 2; ++i)
        #pragma unroll
        for (int j = 0; j < 8; ++j)
            acc[i][j] = (f32x4){0.f, 0.f, 0.f, 0.f};

    const int sm = t & 127;              // staging row/col
    const int sh = t >> 7;               // staging k-half (0..1)

    for (int kt = 0; kt < 10; ++kt) {
        const int kb = kt * 32 + sh * 16;

        // ---- stage A: emb[m0+sm][kb..kb+15] -> As[sm][sh*16..] ----
        {
            float v[16];
            if (kt < 9) {
                const float4* src = (const float4*)(emb + (size_t)(m0 + sm) * DD + kb);
                float4 v0 = src[0], v1 = src[1], v2 = src[2], v3 = src[3];
                v[0]=v0.x; v[1]=v0.y; v[2]=v0.z; v[3]=v0.w;
                v[4]=v1.x; v[5]=v1.y; v[6]=v1.z; v[7]=v1.w;
                v[8]=v2.x; v[9]=v2.y; v[10]=v2.z; v[11]=v2.w;
                v[12]=v3.x; v[13]=v3.y; v[14]=v3.z; v[15]=v3.w;
            } else {
                #pragma unroll
                for (int j = 0; j < 16; ++j) {
                    int k = kb + j;
                    v[j] = (k < DD) ? emb[(size_t)(m0 + sm) * DD + k] : 0.f;
                }
            }
            half2_t p[8];
            #pragma unroll
            for (int j = 0; j < 8; ++j)
                p[j] = __builtin_amdgcn_cvt_pkrtz(v[2*j], v[2*j+1]);
            *(float4*)&As[sm][sh * 16]     = *(float4*)&p[0];
            *(float4*)&As[sm][sh * 16 + 8] = *(float4*)&p[4];
        }
        // ---- stage B: W[kb+j][cb+sm] -> Bs[sm][sh*16..] (transpose) ----
        {
            float v[16];
            #pragma unroll
            for (int j = 0; j < 16; ++j) {
                int k = kb + j;
                v[j] = (k < DD) ? Wsrc[(size_t)k * G3 + cb + sm] : 0.f;
            }
            half2_t p[8];
            #pragma unroll
            for (int j = 0; j < 8; ++j)
                p[j] = __builtin_amdgcn_cvt_pkrtz(v[2*j], v[2*j+1]);
            *(float4*)&Bs[sm][sh * 16]     = *(float4*)&p[0];
            *(float4*)&Bs[sm][sh * 16 + 8] = *(float4*)&p[4];
        }
        __syncthreads();

        // ---- compute: wave w owns row-frags {2w, 2w+1}, all 8 col-frags ----
        FragF a[2], bfr[8];
        #pragma unroll
        for (int mf = 0; mf < 2; ++mf)
            a[mf].f4 = *(const f32x4*)&As[lr + 16 * (2 * w + mf)][lg * 8];
        #pragma unroll
        for (int nf = 0; nf < 8; ++nf)
            bfr[nf].f4 = *(const f32x4*)&Bs[lr + 16 * nf][lg * 8];
        #pragma unroll
        for (int mf = 0; mf < 2; ++mf)
            #pragma unroll
            for (int nf = 0; nf < 8; ++nf)
                acc[mf][nf] = __builtin_amdgcn_mfma_f32_16x16x32_f16(
                    a[mf].v, bfr[nf].v, acc[mf][nf], 0, 0, 0);
        __syncthreads();
    }

    // ---- epilogue: + input bias, store (D: col=l&15, row=(l>>4)*4+reg) ----
    float bias_v[8];
    #pragma unroll
    for (int nf = 0; nf < 8; ++nf) bias_v[nf] = bsrc[cb + 16 * nf + lr];

    #pragma unroll
    for (int mf = 0; mf < 2; ++mf)
        #pragma unroll
        for (int nf = 0; nf < 8; ++nf)
            #pragma unroll
            for (int r = 0; r < 4; ++r) {
                int row = m0 + 16 * (2 * w + mf) + lg * 4 + r;
                int col = n0 + 16 * nf + lr;
                P[(size_t)row * NC + col] = acc[mf][nf][r] + bias_v[nf];
            }
}

// ---------------------------------------------------------------------------
// DPP quad-butterfly add (pure VALU, no DS).
// quad_perm[1,0,3,2] = 0xB1 (xor 1), quad_perm[2,3,0,1] = 0x4E (xor 2).
// ---------------------------------------------------------------------------
template<int CTRL>
__device__ __forceinline__ float qp_add(float x) {
    union { float f; int i; } a, r;
    a.f = x;
    r.i = __builtin_amdgcn_update_dpp(0, a.i, CTRL, 0xF, 0xF, true);
    return x + r.f;
}

// ---------------------------------------------------------------------------
// Kernel 2: GRU scan (R8 structure, known-good at 289us) + waves_per_eu(2,2).
// R9 evidence: allocator targets max occupancy absent a waves-per-EU MAX,
// capping arch VGPRs at 64 and parking the 48 f16 U-fragments in AGPRs
// (~48 v_accvgpr_read/step = the measured 206-vs-120 instr inflation).
// We run exactly 1 block/CU (8 waves = 2/EU), so pinning [2,2] raises the
// VGPR cap to 256 at zero occupancy cost.
// ---------------------------------------------------------------------------
#define BAR() asm volatile("s_waitcnt lgkmcnt(0)\n\ts_barrier" ::: "memory")

__global__ __launch_bounds__(512)
__attribute__((amdgpu_waves_per_eu(2, 2)))
void scan_kernel(
    const int*   __restrict__ tokens,
    const float* __restrict__ state_f, const float* __restrict__ state_b,
    const float* __restrict__ Uf, const float* __restrict__ Ub,
    const float* __restrict__ bf, const float* __restrict__ bb,
    const float* __restrict__ P,
    float* __restrict__ out)
{
    const int b = blockIdx.x;
    const int d = blockIdx.y;            // 0 = fwd, 1 = bwd
    const int t = threadIdx.x;           // 0..511
    const int s = t & 3;                 // K-slice
    const int q = t >> 2;                // h column 0..127

    const float* U  = d ? Ub : Uf;
    const float* bv = d ? bb : bf;
    const float* st = d ? state_b : state_f;
    const int    cb = d ? G3 : 0;        // column base into P

    __shared__ __align__(16) half_t hs[2][HH];   // f16 h, double-buffered
    __shared__ int tok_s[TT];

    tok_s[t] = tokens[b * TT + t];       // 512 threads == TT

    // U columns for the three gates of col q, packed f16 pairs along k
    half2_t uz2[16], ur2[16], uh2[16];
    #pragma unroll
    for (int k2 = 0; k2 < 16; ++k2) {
        const float* U0 = U + (size_t)(s * 32 + 2 * k2) * G3;
        const float* U1 = U0 + G3;
        uz2[k2] = __builtin_amdgcn_cvt_pkrtz(U0[q],          U1[q]);
        ur2[k2] = __builtin_amdgcn_cvt_pkrtz(U0[HH + q],     U1[HH + q]);
        uh2[k2] = __builtin_amdgcn_cvt_pkrtz(U0[2 * HH + q], U1[2 * HH + q]);
    }
    const float bz = bv[G3 + q];
    const float br = bv[G3 + HH + q];
    const float bh = bv[G3 + 2 * HH + q];

    float hreg = st[b * HH + q];         // fp32, redundant across the quad
    if (t < HH) hs[0][t] = (half_t)st[b * HH + t];
    __syncthreads();

    // prefetch step-0 xp triple (fp32)
    float xz_n, xr_n, xh_n;
    {
        int tok = tok_s[d ? (TT - 1) : 0];
        const float* pr = P + (size_t)tok * NC + cb;
        xz_n = pr[q]; xr_n = pr[HH + q]; xh_n = pr[2 * HH + q];
    }

    int cur = 0;
    for (int i = 0; i < TT; ++i) {
        const int tcur = d ? (TT - 1 - i) : i;
        const float xz = xz_n, xr = xr_n, xh = xh_n;
        {   // prefetch next step (last iter re-reads same row; harmless)
            int in1 = (i + 1 < TT) ? (i + 1) : i;
            int tok = tok_s[d ? (TT - 1 - in1) : in1];
            const float* pr = P + (size_t)tok * NC + cb;
            xz_n = pr[q]; xr_n = pr[HH + q]; xh_n = pr[2 * HH + q];
        }

        // this lane's 32-k h slice: 16 half2 = 64 B = 4 x ds_read_b128
        half2_t hv[16];
        {
            const float4* hp = (const float4*)&hs[cur][s * 32];
            *(float4*)&hv[0]  = hp[0];
            *(float4*)&hv[4]  = hp[1];
            *(float4*)&hv[8]  = hp[2];
            *(float4*)&hv[12] = hp[3];
        }
        float az = 0.f, ar = 0.f, ah = 0.f;
        #pragma unroll
        for (int k2 = 0; k2 < 16; ++k2) {
            az = __builtin_amdgcn_fdot2(hv[k2], uz2[k2], az, false);
            ar = __builtin_amdgcn_fdot2(hv[k2], ur2[k2], ar, false);
            ah = __builtin_amdgcn_fdot2(hv[k2], uh2[k2], ah, false);
        }
        // quad butterfly: all 4 lanes end with the full sums for col q
        az = qp_add<0xB1>(az); az = qp_add<0x4E>(az);
        ar = qp_add<0xB1>(ar); ar = qp_add<0x4E>(ar);
        ah = qp_add<0xB1>(ah); ah = qp_add<0x4E>(ah);

        // gates (fp32, redundant across quad)
        float z = __builtin_amdgcn_rcpf(1.f + __expf(-(az + bz + xz)));
        float r = __builtin_amdgcn_rcpf(1.f + __expf(-(ar + br + xr)));
        float ph = xh + r * (ah + bh);
        ph = fminf(fmaxf(ph, -15.f), 15.f);
        float e  = __expf(-2.f * ph);
        float hh = (1.f - e) * __builtin_amdgcn_rcpf(1.f + e);      // tanh
        float hn = z * hreg + (1.f - z) * hh;
        hreg = hn;

        const int nxt = cur ^ 1;
        if (s == 0) {
            hs[nxt][q] = (half_t)hn;
            out[((size_t)b * TT + tcur) * 256 + d * HH + q] = hn;
        }
        BAR();           // hs[nxt] visible; all reads of hs[cur] complete
        cur = nxt;
    }

    if (s == 0) {
        // final states: [B*T*256 | h_f (B*H) | h_b (B*H)]
        out[(size_t)BB * TT * 256 + (size_t)d * BB * HH + b * HH + q] = hreg;
    }
}

// ---------------------------------------------------------------------------
extern "C" void kernel_launch(void* const* d_in, const int* in_sizes, int n_in,
                              void* d_out, int out_size, void* d_ws, size_t ws_size,
                              hipStream_t stream)
{
    const int*   tokens  = (const int*)  d_in[0];
    const float* state_f = (const float*)d_in[1];
    const float* state_b = (const float*)d_in[2];
    const float* emb     = (const float*)d_in[3];
    const float* W_f     = (const float*)d_in[4];
    const float* U_f     = (const float*)d_in[5];
    const float* b_f     = (const float*)d_in[6];
    const float* W_b     = (const float*)d_in[7];
    const float* U_b     = (const float*)d_in[8];
    const float* b_b     = (const float*)d_in[9];
    float*       out     = (float*)d_out;

    float* P = (float*)d_ws;   // needs 32000*768*4 = 98.3 MB of workspace

    dim3 gp(VV / 128, NC / 128);           // 250 x 6
    proj_kernel<<<gp, 256, 0, stream>>>(emb, W_f, W_b, b_f, b_b, P);

    dim3 gs(BB, 2);                         // 128 batch x 2 directions
    scan_kernel<<<gs, 512, 0, stream>>>(tokens, state_f, state_b,
                                        U_f, U_b, b_f, b_b, P, out);
}

// Round 11
// 356.256 us; speedup vs baseline: 1.9044x; 1.2002x over previous
//
#include <hip/hip_runtime.h>
#include <stddef.h>

// Sizes (fixed by the problem)
#define BB   128      // batch
#define TT   512      // time
#define VV   32000    // vocab
#define DD   300      // emb dim
#define HH   128      // hidden
#define G3   384      // 3*H
#define NC   768      // 2*3*H (fwd+bwd projected gates)

typedef __fp16 half2_t __attribute__((ext_vector_type(2)));
typedef _Float16 f16x8 __attribute__((ext_vector_type(8)));   // MFMA A/B frag
typedef float    f32x4 __attribute__((ext_vector_type(4)));   // MFMA C/D frag

union FragF {
    f16x8    v;      // MFMA operand
    _Float16 h[8];   // element fill
    f32x4    f4;     // 16B LDS read
};

// lgkm-only barrier: no forced vmcnt(0) drain (compiler still inserts vmcnt
// waits at actual data dependencies).
#define BAR() asm volatile("s_waitcnt lgkmcnt(0)\n\ts_barrier" ::: "memory")

// ---------------------------------------------------------------------------
// Kernel 1: P[v][g] = emb[v][:] @ Wcat[:, g] + b_i[g] -- MFMA GEMM with a
// 2-deep register pipeline: kt+1's global loads issue BEFORE kt's MFMA
// (latency hides under frag reads + 16 MFMA), cvt+LDS-store after barrier.
// Fragment conventions (hardware-verified R9/R10):
//   A: lane l holds A[row=l&15][k=8*(l>>4)+j]   B: B[k=8*(l>>4)+j][col=l&15]
//   D: col=l&15, row=(l>>4)*4+reg
// ---------------------------------------------------------------------------
#define ASTR 40
__global__ __launch_bounds__(256) void proj_kernel(
    const float* __restrict__ emb,
    const float* __restrict__ Wf, const float* __restrict__ Wb,
    const float* __restrict__ bf, const float* __restrict__ bb,
    float* __restrict__ P)
{
    __shared__ __align__(16) _Float16 As[128][ASTR];
    __shared__ __align__(16) _Float16 Bs[128][ASTR];

    const int m0 = blockIdx.x * 128;     // vocab-row tile
    const int n0 = blockIdx.y * 128;     // output-col tile

    const float* Wsrc;
    const float* bsrc;
    int cb;
    if (n0 < G3) { Wsrc = Wf; bsrc = bf; cb = n0; }
    else         { Wsrc = Wb; bsrc = bb; cb = n0 - G3; }

    const int t  = threadIdx.x;
    const int w  = t >> 6;               // wave 0..3
    const int l  = t & 63;
    const int lr = l & 15;
    const int lg = l >> 4;               // 0..3

    f32x4 acc[2][8];
    #pragma unroll
    for (int i = 0; i < 2; ++i)
        #pragma unroll
        for (int j = 0; j < 8; ++j)
            acc[i][j] = (f32x4){0.f, 0.f, 0.f, 0.f};

    const int sm = t & 127;              // staging row/col
    const int sh = t >> 7;               // staging k-half (0..1)

    float va[16], vb[16];

#define LOAD_TILE(KT)                                                         \
    {                                                                         \
        const int kb_ = (KT) * 32 + sh * 16;                                  \
        if ((KT) < 9) {                                                       \
            const float4* srcA = (const float4*)(emb + (size_t)(m0 + sm) * DD + kb_); \
            float4 a0 = srcA[0], a1 = srcA[1], a2 = srcA[2], a3 = srcA[3];    \
            va[0]=a0.x; va[1]=a0.y; va[2]=a0.z; va[3]=a0.w;                   \
            va[4]=a1.x; va[5]=a1.y; va[6]=a1.z; va[7]=a1.w;                   \
            va[8]=a2.x; va[9]=a2.y; va[10]=a2.z; va[11]=a2.w;                 \
            va[12]=a3.x; va[13]=a3.y; va[14]=a3.z; va[15]=a3.w;               \
            _Pragma("unroll")                                                 \
            for (int j = 0; j < 16; ++j)                                      \
                vb[j] = Wsrc[(size_t)(kb_ + j) * G3 + cb + sm];               \
        } else {                                                              \
            _Pragma("unroll")                                                 \
            for (int j = 0; j < 16; ++j) {                                    \
                int k_ = kb_ + j;                                             \
                va[j] = (k_ < DD) ? emb[(size_t)(m0 + sm) * DD + k_] : 0.f;   \
                vb[j] = (k_ < DD) ? Wsrc[(size_t)k_ * G3 + cb + sm] : 0.f;    \
            }                                                                 \
        }                                                                     \
    }

#define STORE_TILE()                                                          \
    {                                                                         \
        half2_t pa[8], pb[8];                                                 \
        _Pragma("unroll")                                                     \
        for (int j = 0; j < 8; ++j) {                                         \
            pa[j] = __builtin_amdgcn_cvt_pkrtz(va[2*j], va[2*j+1]);           \
            pb[j] = __builtin_amdgcn_cvt_pkrtz(vb[2*j], vb[2*j+1]);           \
        }                                                                     \
        *(float4*)&As[sm][sh * 16]     = *(float4*)&pa[0];                    \
        *(float4*)&As[sm][sh * 16 + 8] = *(float4*)&pa[4];                    \
        *(float4*)&Bs[sm][sh * 16]     = *(float4*)&pb[0];                    \
        *(float4*)&Bs[sm][sh * 16 + 8] = *(float4*)&pb[4];                    \
    }

    // prologue: tile 0 into LDS
    LOAD_TILE(0);
    STORE_TILE();
    BAR();

    for (int kt = 0; kt < 10; ++kt) {
        if (kt < 9) LOAD_TILE(kt + 1);   // issue early; latency hides below

        FragF a[2], bfr[8];
        #pragma unroll
        for (int mf = 0; mf < 2; ++mf)
            a[mf].f4 = *(const f32x4*)&As[lr + 16 * (2 * w + mf)][lg * 8];
        #pragma unroll
        for (int nf = 0; nf < 8; ++nf)
            bfr[nf].f4 = *(const f32x4*)&Bs[lr + 16 * nf][lg * 8];
        #pragma unroll
        for (int mf = 0; mf < 2; ++mf)
            #pragma unroll
            for (int nf = 0; nf < 8; ++nf)
                acc[mf][nf] = __builtin_amdgcn_mfma_f32_16x16x32_f16(
                    a[mf].v, bfr[nf].v, acc[mf][nf], 0, 0, 0);
        BAR();                            // all waves done reading LDS
        if (kt < 9) STORE_TILE();
        BAR();                            // stores visible
    }

    // ---- epilogue: + input bias, store (D: col=l&15, row=(l>>4)*4+reg) ----
    float bias_v[8];
    #pragma unroll
    for (int nf = 0; nf < 8; ++nf) bias_v[nf] = bsrc[cb + 16 * nf + lr];

    #pragma unroll
    for (int mf = 0; mf < 2; ++mf)
        #pragma unroll
        for (int nf = 0; nf < 8; ++nf)
            #pragma unroll
            for (int r = 0; r < 4; ++r) {
                int row = m0 + 16 * (2 * w + mf) + lg * 4 + r;
                int col = n0 + 16 * nf + lr;
                P[(size_t)row * NC + col] = acc[mf][nf][r] + bias_v[nf];
            }
#undef LOAD_TILE
#undef STORE_TILE
}

// ---------------------------------------------------------------------------
// Kernel 2: GRU scan via per-(b,d) MFMA matvec (M=1 broadcast trick).
// grid (128 batch, 2 dirs) x 512 threads (8 waves), 1 block/CU.
// Per step: rec[384] = h[128] @ U[128x384] as 12 mfma_f32_16x16x32_f16 per
// wave: wave w owns cols c=16w+lr for ALL 3 gates (z,r,hh accs). h is
// broadcast into all 16 A-rows (A-frag read ignores lr) -> every D row
// equals rec -> EVERY lane's acc[0] holds its column's full sum: gate math
// on all 64 lanes, no butterfly, no LDS exchange. lg==0 lane writes h/out.
// U fragments (48 regs) feed MFMA directly -> AGPR placement is free
// (kills the v_accvgpr_read tax that capped the fdot2 path at ~290us).
// One lgkm-only barrier per step. Tokens prefetched 2 ahead, xp 1 ahead.
// ---------------------------------------------------------------------------
__global__ __launch_bounds__(512) void scan_kernel(
    const int*   __restrict__ tokens,
    const float* __restrict__ state_f, const float* __restrict__ state_b,
    const float* __restrict__ Uf, const float* __restrict__ Ub,
    const float* __restrict__ bf, const float* __restrict__ bb,
    const float* __restrict__ P,
    float* __restrict__ out)
{
    const int b  = blockIdx.x;
    const int d  = blockIdx.y;           // 0 = fwd, 1 = bwd
    const int t  = threadIdx.x;          // 0..511
    const int w  = t >> 6;               // wave 0..7
    const int l  = t & 63;
    const int lr = l & 15;
    const int lg = l >> 4;               // 0..3
    const int c  = w * 16 + lr;          // gate column 0..127

    const float* U  = d ? Ub : Uf;
    const float* bv = d ? bb : bf;
    const float* st = d ? state_b : state_f;
    const int    cb = d ? G3 : 0;

    __shared__ __align__(16) _Float16 hs[2][HH];   // f16 h, double-buffered
    __shared__ int tok_s[TT];

    tok_s[t] = tokens[b * TT + t];       // 512 threads == TT

    // B-fragments: gate g, K-tile kt: B[k=kt*32+lg*8+j][col = g*128 + c]
    FragF Bz[4], Br[4], Bh[4];
    #pragma unroll
    for (int kt = 0; kt < 4; ++kt)
        #pragma unroll
        for (int j = 0; j < 8; ++j) {
            const float* Urow = U + (size_t)(kt * 32 + lg * 8 + j) * G3 + c;
            Bz[kt].h[j] = (_Float16)Urow[0];
            Br[kt].h[j] = (_Float16)Urow[HH];
            Bh[kt].h[j] = (_Float16)Urow[2 * HH];
        }
    const float bz = bv[G3 + c];
    const float brc = bv[G3 + HH + c];
    const float bhc = bv[G3 + 2 * HH + c];

    float hreg = st[b * HH + c];         // valid in every lane of col c
    if (t < HH) hs[0][t] = (_Float16)st[b * HH + t];
    __syncthreads();

    // token/xp prefetch: tokB = token for step it+1 (register, no LDS dep)
    float xz_n, xr_n, xh_n;
    int   tokB;
    {
        int tok0 = tok_s[d ? (TT - 1) : 0];
        const float* pr = P + (size_t)tok0 * NC + cb + c;
        xz_n = pr[0]; xr_n = pr[HH]; xh_n = pr[2 * HH];
        tokB = tok_s[d ? (TT - 2) : 1];
    }

    int cur = 0;
    for (int it = 0; it < TT; ++it) {
        const int tcur = d ? (TT - 1 - it) : it;
        const float xz = xz_n, xr = xr_n, xh = xh_n;
        {   // issue next step's xp loads immediately (token already in reg)
            const float* pr = P + (size_t)tokB * NC + cb + c;
            xz_n = pr[0]; xr_n = pr[HH]; xh_n = pr[2 * HH];
            int i2 = (it + 2 < TT) ? (it + 2) : (TT - 1);
            tokB = tok_s[d ? (TT - 1 - i2) : i2];
        }

        // A-frags: broadcast h into all 16 rows (addr independent of lr)
        FragF a[4];
        #pragma unroll
        for (int kt = 0; kt < 4; ++kt)
            a[kt].f4 = *(const f32x4*)&hs[cur][kt * 32 + lg * 8];

        f32x4 az = {0.f,0.f,0.f,0.f}, ar = {0.f,0.f,0.f,0.f}, ah = {0.f,0.f,0.f,0.f};
        #pragma unroll
        for (int kt = 0; kt < 4; ++kt) {
            az = __builtin_amdgcn_mfma_f32_16x16x32_f16(a[kt].v, Bz[kt].v, az, 0, 0, 0);
            ar = __builtin_amdgcn_mfma_f32_16x16x32_f16(a[kt].v, Br[kt].v, ar, 0, 0, 0);
            ah = __builtin_amdgcn_mfma_f32_16x16x32_f16(a[kt].v, Bh[kt].v, ah, 0, 0, 0);
        }

        // gates: every lane's acc[0] = full sum for col c (rows identical)
        float z  = __builtin_amdgcn_rcpf(1.f + __expf(-(az[0] + bz  + xz)));
        float r  = __builtin_amdgcn_rcpf(1.f + __expf(-(ar[0] + brc + xr)));
        float ph = xh + r * (ah[0] + bhc);
        ph = fminf(fmaxf(ph, -15.f), 15.f);
        float e   = __expf(-2.f * ph);
        float hhv = (1.f - e) * __builtin_amdgcn_rcpf(1.f + e);     // tanh
        float hn  = z * hreg + (1.f - z) * hhv;
        hreg = hn;

        const int nxt = cur ^ 1;
        if (lg == 0) {
            hs[nxt][c] = (_Float16)hn;
            out[((size_t)b * TT + tcur) * 256 + d * HH + c] = hn;
        }
        BAR();           // hs[nxt] visible; all reads of hs[cur] retired
        cur = nxt;
    }

    if (lg == 0) {
        // final states: [B*T*256 | h_f (B*H) | h_b (B*H)]
        out[(size_t)BB * TT * 256 + (size_t)d * BB * HH + b * HH + c] = hreg;
    }
}

// ---------------------------------------------------------------------------
extern "C" void kernel_launch(void* const* d_in, const int* in_sizes, int n_in,
                              void* d_out, int out_size, void* d_ws, size_t ws_size,
                              hipStream_t stream)
{
    const int*   tokens  = (const int*)  d_in[0];
    const float* state_f = (const float*)d_in[1];
    const float* state_b = (const float*)d_in[2];
    const float* emb     = (const float*)d_in[3];
    const float* W_f     = (const float*)d_in[4];
    const float* U_f     = (const float*)d_in[5];
    const float* b_f     = (const float*)d_in[6];
    const float* W_b     = (const float*)d_in[7];
    const float* U_b     = (const float*)d_in[8];
    const float* b_b     = (const float*)d_in[9];
    float*       out     = (float*)d_out;

    float* P = (float*)d_ws;   // needs 32000*768*4 = 98.3 MB of workspace

    dim3 gp(VV / 128, NC / 128);           // 250 x 6
    proj_kernel<<<gp, 256, 0, stream>>>(emb, W_f, W_b, b_f, b_b, P);

    dim3 gs(BB, 2);                         // 128 batch x 2 directions
    scan_kernel<<<gs, 512, 0, stream>>>(tokens, state_f, state_b,
                                        U_f, U_b, b_f, b_b, P, out);
}